// Round 1
// baseline (764.390 us; speedup 1.0000x reference)
//
#include <hip/hip_runtime.h>
#include <math.h>

#define B 64
#define D 256
#define M 8000
#define N 32
#define V 50000
#define LG_LD 8000
#define SE_STRIDE 260   // padded fp32 stride for E rows (260%32==4 -> bank-spread)
#define EPB 16          // entries per block in heavy kernel

// ---------------- vq = query @ qproj_w^T + qproj_b ----------------
__global__ __launch_bounds__(256) void k_vq(const float* __restrict__ q,
                                            const float* __restrict__ W,
                                            const float* __restrict__ bias,
                                            float* __restrict__ vq) {
    int b = blockIdx.x, t = threadIdx.x;
    __shared__ float qs[D];
    qs[t] = q[b * D + t];
    __syncthreads();
    const float* wr = W + t * D;   // row d = t of qproj_w
    float acc = bias[t];
#pragma unroll 8
    for (int k = 0; k < D; k += 4) {
        float4 w4 = *(const float4*)(wr + k);
        acc += qs[k] * w4.x + qs[k + 1] * w4.y + qs[k + 2] * w4.z + qs[k + 3] * w4.w;
    }
    vq[b * D + t] = acc;
}

// ---------------- keys_e[j][:] = wordemb[keys[j]] * mask ----------------
__global__ __launch_bounds__(256) void k_embed_keys(const int* __restrict__ keys,
                                                    const float* __restrict__ emb,
                                                    float* __restrict__ keys_e) {
    int gid = blockIdx.x * 256 + threadIdx.x;   // over 8000*64 float4s
    int j = gid >> 6, q = gid & 63;
    int id = keys[j];
    const float4* emb4 = (const float4*)emb;
    float4 v = emb4[id * (D / 4) + q];
    if (id == 0) { v.x = 0.f; v.y = 0.f; v.z = 0.f; v.w = 0.f; }
    ((float4*)keys_e)[j * (D / 4) + q] = v;
}

// ---------------- logits_e = query @ keys_e^T  (64 x 8000) ----------------
// grid 250 blocks, each a j-tile of 32 (all 64 b). LDS: keys tile only.
__global__ __launch_bounds__(256) void k_logits(const float* __restrict__ q,
                                                const float* __restrict__ keys_e,
                                                float* __restrict__ out_lg) {
    __shared__ float ks[32 * SE_STRIDE];   // 33,280 B
    int t = threadIdx.x;
    int j0 = blockIdx.x * 32;
    for (int i = 0; i < 32; ++i)
        ks[i * SE_STRIDE + t] = keys_e[(j0 + i) * D + t];
    __syncthreads();
    int tx = t & 15, ty = t >> 4;   // j = tx + 16*j2 ; b = ty + 16*i
    float acc[4][2] = {};
    for (int k = 0; k < D; k += 4) {
        float4 c0 = *(const float4*)&ks[tx * SE_STRIDE + k];
        float4 c1 = *(const float4*)&ks[(tx + 16) * SE_STRIDE + k];
#pragma unroll
        for (int i = 0; i < 4; ++i) {
            float4 a = *(const float4*)&q[(ty + 16 * i) * D + k];
            acc[i][0] += a.x * c0.x + a.y * c0.y + a.z * c0.z + a.w * c0.w;
            acc[i][1] += a.x * c1.x + a.y * c1.y + a.z * c1.z + a.w * c1.w;
        }
    }
#pragma unroll
    for (int i = 0; i < 4; ++i) {
        out_lg[(ty + 16 * i) * LG_LD + j0 + tx] = acc[i][0];
        out_lg[(ty + 16 * i) * LG_LD + j0 + tx + 16] = acc[i][1];
    }
}

// ---------------- per-b row max & 1/sum(exp) over m=8000 ----------------
__global__ __launch_bounds__(256) void k_stats(const float* __restrict__ lg,
                                               float* __restrict__ rmax,
                                               float* __restrict__ rsinv) {
    int b = blockIdx.x, t = threadIdx.x;
    __shared__ float red[256];
    const float* row = lg + b * LG_LD;
    float mx = -INFINITY;
    for (int j = t; j < M; j += 256) mx = fmaxf(mx, row[j]);
    red[t] = mx; __syncthreads();
    for (int s = 128; s > 0; s >>= 1) {
        if (t < s) red[t] = fmaxf(red[t], red[t + s]);
        __syncthreads();
    }
    mx = red[0]; __syncthreads();
    float sm = 0.f;
    for (int j = t; j < M; j += 256) sm += __expf(row[j] - mx);
    red[t] = sm; __syncthreads();
    for (int s = 128; s > 0; s >>= 1) {
        if (t < s) red[t] += red[t + s];
        __syncthreads();
    }
    if (t == 0) { rmax[b] = mx; rsinv[b] = 1.f / red[0]; }
}

// ---------------- wT[m][b] = prob_e[b][m]  (transposed for broadcast) ----------------
__global__ __launch_bounds__(256) void k_w(const float* __restrict__ lg,
                                           const float* __restrict__ rmax,
                                           const float* __restrict__ rsinv,
                                           float* __restrict__ wT) {
    int idx = blockIdx.x * 256 + threadIdx.x;   // 512000 total
    int m = idx >> 6, b = idx & 63;
    wT[idx] = __expf(lg[b * LG_LD + m] - rmax[b]) * rsinv[b];
}

// ---------------- o_k = prob_e @ keys_e ----------------
// grid 128: 4 b-groups x 32 j-chunks of 250. thread t = d column. atomicAdd finish.
__global__ __launch_bounds__(256) void k_ok(const float* __restrict__ keys_e,
                                            const float* __restrict__ wT,
                                            float* __restrict__ o_k) {
    int t = threadIdx.x;
    int bg = blockIdx.x >> 5;    // 0..3 -> b range [bg*16, bg*16+16)
    int jc = blockIdx.x & 31;    // 0..31 -> 250 j's
    int j0 = jc * 250;
    float acc[16] = {};
    for (int j = j0; j < j0 + 250; ++j) {
        float kv = keys_e[j * D + t];
        const float4* w4 = (const float4*)(wT + j * 64 + bg * 16);
        float4 wa = w4[0], wb = w4[1], wc = w4[2], wd = w4[3];
        acc[0]  += wa.x * kv; acc[1]  += wa.y * kv; acc[2]  += wa.z * kv; acc[3]  += wa.w * kv;
        acc[4]  += wb.x * kv; acc[5]  += wb.y * kv; acc[6]  += wb.z * kv; acc[7]  += wb.w * kv;
        acc[8]  += wc.x * kv; acc[9]  += wc.y * kv; acc[10] += wc.z * kv; acc[11] += wc.w * kv;
        acc[12] += wd.x * kv; acc[13] += wd.y * kv; acc[14] += wd.z * kv; acc[15] += wd.w * kv;
    }
#pragma unroll
    for (int i = 0; i < 16; ++i)
        atomicAdd(&o_k[(bg * 16 + i) * D + t], acc[i]);
}

// ---------------- heavy: per-entry value attention, fused with prob_e weighting ----------------
// grid 500 blocks x EPB=16 entries. combined accumulated in registers across entries.
__global__ __launch_bounds__(256, 2) void k_heavy(const int* __restrict__ entries,
                                                  const float* __restrict__ emb,
                                                  const float* __restrict__ vq,
                                                  const float* __restrict__ wT,
                                                  float* __restrict__ comb) {
    __shared__ float sE[N * SE_STRIDE];   // 33,280 B
    __shared__ float sP[N * 64];          // n-major P*prob_e, 8,192 B
    __shared__ float sw[64];
    int t = threadIdx.x;
    // S-phase ids: microtile 4b x 2n
    int nx = t & 15, ty = t >> 4;
    int n0 = nx * 2, b0 = ty * 4;
    // PV-phase ids: microtile 8b x 8d
    int l = t & 31, g = t >> 5;           // d0 = 8*l, b range [8*g, 8*g+8)
    float acc[8][8] = {};                 // combined accumulator, carried across entries
    int m0 = blockIdx.x * EPB;
    const float4* emb4 = (const float4*)emb;

    for (int e = 0; e < EPB; ++e) {
        int m = m0 + e;
        __syncthreads();   // prev entry's PV reads of sE/sP done
        // ---- load E tile (32 rows x 256, masked) ----
        const int* ent = entries + m * N;
        {
            int rsub = t >> 6, q = t & 63;
#pragma unroll
            for (int r4 = 0; r4 < 8; ++r4) {
                int r = r4 * 4 + rsub;
                int id = ent[r];
                float4 v = emb4[id * (D / 4) + q];
                if (id == 0) { v.x = 0.f; v.y = 0.f; v.z = 0.f; v.w = 0.f; }
                *(float4*)&sE[r * SE_STRIDE + q * 4] = v;
            }
        }
        if (t < 64) sw[t] = wT[m * 64 + t];
        __syncthreads();
        // ---- S = vq @ E^T (64 x 32) ----
        float s[4][2] = {};
        for (int k = 0; k < D; k += 4) {
            float4 e0 = *(const float4*)&sE[n0 * SE_STRIDE + k];
            float4 e1 = *(const float4*)&sE[(n0 + 1) * SE_STRIDE + k];
#pragma unroll
            for (int i = 0; i < 4; ++i) {
                float4 a = *(const float4*)&vq[(b0 + i) * D + k];
                s[i][0] += a.x * e0.x + a.y * e0.y + a.z * e0.z + a.w * e0.w;
                s[i][1] += a.x * e1.x + a.y * e1.y + a.z * e1.z + a.w * e1.w;
            }
        }
        // ---- softmax over n (16-lane groups), fold prob_e[b][m] ----
        float p0[4], p1[4];
#pragma unroll
        for (int i = 0; i < 4; ++i) {
            float mx = fmaxf(s[i][0], s[i][1]);
            for (int off = 1; off < 16; off <<= 1) mx = fmaxf(mx, __shfl_xor(mx, off, 16));
            float e0 = __expf(s[i][0] - mx), e1 = __expf(s[i][1] - mx);
            float sum = e0 + e1;
            for (int off = 1; off < 16; off <<= 1) sum += __shfl_xor(sum, off, 16);
            float sc = sw[b0 + i] / sum;
            p0[i] = e0 * sc; p1[i] = e1 * sc;
        }
        // write P (n-major): sP[n][b0..b0+3]
        *(float4*)&sP[n0 * 64 + b0] = make_float4(p0[0], p0[1], p0[2], p0[3]);
        *(float4*)&sP[(n0 + 1) * 64 + b0] = make_float4(p1[0], p1[1], p1[2], p1[3]);
        __syncthreads();
        // ---- PV: acc[b][d] += sum_n P[n][b] * E[n][d] ----
        const float4* sE4 = (const float4*)sE;
        const float4* sP4 = (const float4*)sP;
#pragma unroll 4
        for (int n = 0; n < N; ++n) {
            float4 eA = sE4[n * (SE_STRIDE / 4) + 2 * l];
            float4 eB = sE4[n * (SE_STRIDE / 4) + 2 * l + 1];
            float4 pA = sP4[n * 16 + g * 2];
            float4 pB = sP4[n * 16 + g * 2 + 1];
            float pv[8] = {pA.x, pA.y, pA.z, pA.w, pB.x, pB.y, pB.z, pB.w};
#pragma unroll
            for (int bb = 0; bb < 8; ++bb) {
                acc[bb][0] += pv[bb] * eA.x; acc[bb][1] += pv[bb] * eA.y;
                acc[bb][2] += pv[bb] * eA.z; acc[bb][3] += pv[bb] * eA.w;
                acc[bb][4] += pv[bb] * eB.x; acc[bb][5] += pv[bb] * eB.y;
                acc[bb][6] += pv[bb] * eB.z; acc[bb][7] += pv[bb] * eB.w;
            }
        }
    }
    // ---- epilogue: combined += acc ----
#pragma unroll
    for (int bb = 0; bb < 8; ++bb)
#pragma unroll
        for (int q2 = 0; q2 < 8; ++q2)
            atomicAdd(&comb[(g * 8 + bb) * D + l * 8 + q2], acc[bb][q2]);
}

extern "C" void kernel_launch(void* const* d_in, const int* in_sizes, int n_in,
                              void* d_out, int out_size, void* d_ws, size_t ws_size,
                              hipStream_t stream) {
    const int*   keys    = (const int*)d_in[0];
    const int*   entries = (const int*)d_in[1];
    const float* query   = (const float*)d_in[2];
    const float* wordemb = (const float*)d_in[3];
    const float* qproj_w = (const float*)d_in[4];
    const float* qproj_b = (const float*)d_in[5];

    float* out   = (float*)d_out;
    float* o_k   = out;                       // 16384
    float* lg    = out + B * D;               // 512000
    float* comb  = out + B * D + B * M;       // 16384

    float* ws     = (float*)d_ws;
    float* vq     = ws;                        // 16384
    float* keys_e = ws + 16384;                // 2,048,000
    float* wT     = keys_e + M * D;            // 512,000
    float* rmax   = wT + M * B;                // 64
    float* rsinv  = rmax + 64;                 // 64

    // zero atomic-accumulated outputs
    hipMemsetAsync(o_k, 0, B * D * sizeof(float), stream);
    hipMemsetAsync(comb, 0, B * D * sizeof(float), stream);

    k_vq<<<B, 256, 0, stream>>>(query, qproj_w, qproj_b, vq);
    k_embed_keys<<<(M * (D / 4)) / 256, 256, 0, stream>>>(keys, wordemb, keys_e);
    k_logits<<<M / 32, 256, 0, stream>>>(query, keys_e, lg);
    k_stats<<<B, 256, 0, stream>>>(lg, rmax, rsinv);
    k_w<<<(M * B) / 256, 256, 0, stream>>>(lg, rmax, rsinv, wT);
    k_ok<<<128, 256, 0, stream>>>(keys_e, wT, o_k);
    k_heavy<<<M / EPB, 256, 0, stream>>>(entries, wordemb, vq, wT, comb);
}

// Round 2
// 265.249 us; speedup vs baseline: 2.8818x; 2.8818x over previous
//
#include <hip/hip_runtime.h>
#include <math.h>

#define B 64
#define D 256
#define M 8000
#define N 32
#define LG_LD 8000
#define EPB 16

typedef unsigned short u16;
typedef __bf16 bf16x8 __attribute__((ext_vector_type(8)));
typedef float fx4 __attribute__((ext_vector_type(4)));

#define STR_E  264   // bf16 stride of sE rows (n-major), 16B-aligned rows
#define STR_ET 40    // bf16 stride of sET rows (d-major)
#define STR_P  40    // bf16 stride of sP rows (b-major)

static __device__ __forceinline__ u16 f2bf(float x) {
    unsigned int u = __float_as_uint(x);
    u += 0x7FFFu + ((u >> 16) & 1u);
    return (u16)(u >> 16);
}

// ---------------- vq = query @ qproj_w^T + qproj_b  (bf16 out) ----------------
__global__ __launch_bounds__(256) void k_vq(const float* __restrict__ q,
                                            const float* __restrict__ W,
                                            const float* __restrict__ bias,
                                            u16* __restrict__ vqb) {
    int b = blockIdx.x, t = threadIdx.x;
    __shared__ float qs[D];
    qs[t] = q[b * D + t];
    __syncthreads();
    const float* wr = W + t * D;
    float acc = bias[t];
#pragma unroll 8
    for (int k = 0; k < D; k += 4) {
        float4 w4 = *(const float4*)(wr + k);
        acc += qs[k] * w4.x + qs[k + 1] * w4.y + qs[k + 2] * w4.z + qs[k + 3] * w4.w;
    }
    vqb[b * D + t] = f2bf(acc);
}

// ---------------- keys_e[j][:] = wordemb[keys[j]] * mask ----------------
__global__ __launch_bounds__(256) void k_embed_keys(const int* __restrict__ keys,
                                                    const float* __restrict__ emb,
                                                    float* __restrict__ keys_e) {
    int gid = blockIdx.x * 256 + threadIdx.x;
    int j = gid >> 6, qq = gid & 63;
    int id = keys[j];
    const float4* emb4 = (const float4*)emb;
    float4 v = emb4[id * (D / 4) + qq];
    if (id == 0) { v.x = 0.f; v.y = 0.f; v.z = 0.f; v.w = 0.f; }
    ((float4*)keys_e)[j * (D / 4) + qq] = v;
}

// ---------------- logits_e = query @ keys_e^T  (64 x 8000, fp32) ----------------
__global__ __launch_bounds__(256) void k_logits(const float* __restrict__ q,
                                                const float* __restrict__ keys_e,
                                                float* __restrict__ out_lg) {
    __shared__ float ks[32 * 260];
    int t = threadIdx.x;
    int j0 = blockIdx.x * 32;
    for (int i = 0; i < 32; ++i)
        ks[i * 260 + t] = keys_e[(j0 + i) * D + t];
    __syncthreads();
    int tx = t & 15, ty = t >> 4;
    float acc[4][2] = {};
    for (int k = 0; k < D; k += 4) {
        float4 c0 = *(const float4*)&ks[tx * 260 + k];
        float4 c1 = *(const float4*)&ks[(tx + 16) * 260 + k];
#pragma unroll
        for (int i = 0; i < 4; ++i) {
            float4 a = *(const float4*)&q[(ty + 16 * i) * D + k];
            acc[i][0] += a.x * c0.x + a.y * c0.y + a.z * c0.z + a.w * c0.w;
            acc[i][1] += a.x * c1.x + a.y * c1.y + a.z * c1.z + a.w * c1.w;
        }
    }
#pragma unroll
    for (int i = 0; i < 4; ++i) {
        out_lg[(ty + 16 * i) * LG_LD + j0 + tx] = acc[i][0];
        out_lg[(ty + 16 * i) * LG_LD + j0 + tx + 16] = acc[i][1];
    }
}

// ---------------- per-b row max & 1/sum(exp) over m ----------------
__global__ __launch_bounds__(256) void k_stats(const float* __restrict__ lg,
                                               float* __restrict__ rmax,
                                               float* __restrict__ rsinv) {
    int b = blockIdx.x, t = threadIdx.x;
    __shared__ float red[256];
    const float* row = lg + b * LG_LD;
    float mx = -INFINITY;
    for (int j = t; j < M; j += 256) mx = fmaxf(mx, row[j]);
    red[t] = mx; __syncthreads();
    for (int s = 128; s > 0; s >>= 1) {
        if (t < s) red[t] = fmaxf(red[t], red[t + s]);
        __syncthreads();
    }
    mx = red[0]; __syncthreads();
    float sm = 0.f;
    for (int j = t; j < M; j += 256) sm += __expf(row[j] - mx);
    red[t] = sm; __syncthreads();
    for (int s = 128; s > 0; s >>= 1) {
        if (t < s) red[t] += red[t + s];
        __syncthreads();
    }
    if (t == 0) { rmax[b] = mx; rsinv[b] = 1.f / red[0]; }
}

// ---------------- wT[m][b] = prob_e[b][m] ----------------
__global__ __launch_bounds__(256) void k_w(const float* __restrict__ lg,
                                           const float* __restrict__ rmax,
                                           const float* __restrict__ rsinv,
                                           float* __restrict__ wT) {
    int idx = blockIdx.x * 256 + threadIdx.x;
    int m = idx >> 6, b = idx & 63;
    wT[idx] = __expf(lg[b * LG_LD + m] - rmax[b]) * rsinv[b];
}

// ---------------- o_k = prob_e @ keys_e ----------------
__global__ __launch_bounds__(256) void k_ok(const float* __restrict__ keys_e,
                                            const float* __restrict__ wT,
                                            float* __restrict__ o_k) {
    int t = threadIdx.x;
    int bg = blockIdx.x >> 5;
    int jc = blockIdx.x & 31;
    int j0 = jc * 250;
    float acc[16] = {};
    for (int j = j0; j < j0 + 250; ++j) {
        float kv = keys_e[j * D + t];
        const float4* w4 = (const float4*)(wT + j * 64 + bg * 16);
        float4 wa = w4[0], wb = w4[1], wc = w4[2], wd = w4[3];
        acc[0]  += wa.x * kv; acc[1]  += wa.y * kv; acc[2]  += wa.z * kv; acc[3]  += wa.w * kv;
        acc[4]  += wb.x * kv; acc[5]  += wb.y * kv; acc[6]  += wb.z * kv; acc[7]  += wb.w * kv;
        acc[8]  += wc.x * kv; acc[9]  += wc.y * kv; acc[10] += wc.z * kv; acc[11] += wc.w * kv;
        acc[12] += wd.x * kv; acc[13] += wd.y * kv; acc[14] += wd.z * kv; acc[15] += wd.w * kv;
    }
#pragma unroll
    for (int i = 0; i < 16; ++i)
        atomicAdd(&o_k[(bg * 16 + i) * D + t], acc[i]);
}

// ---------------- heavy: per-entry value attention via bf16 MFMA ----------------
// S^T(n x b) = E . vq^T  (K=d=256, mfma_f32_16x16x32_bf16, 16 MFMA/wave)
// softmax over n in regs+shfl, prob_e folded; P -> LDS bf16
// combined(b x d) += P . E  (K=n=32, 16 MFMA/wave), acc carried over 16 entries
__global__ __launch_bounds__(256, 2) void k_heavy(const int* __restrict__ entries,
                                                  const float* __restrict__ emb,
                                                  const u16* __restrict__ vqb,
                                                  const float* __restrict__ wTp,
                                                  float* __restrict__ comb) {
    __shared__ __align__(16) u16 sEu[N * STR_E];     // 16,896 B  row-major E (n x d)
    __shared__ __align__(16) u16 sETu[D * STR_ET];   // 20,480 B  transposed E (d x n)
    __shared__ __align__(16) u16 sPu[B * STR_P];     //  5,120 B  P (b x n)
    __shared__ float sw[B];

    int t = threadIdx.x;
    int lane = t & 63, l = lane & 15, q = lane >> 4, w = t >> 6;
    int b0 = 16 * w;
    int sn = t & 31, sg = t >> 5;          // staging: row n = sn, d4-chunks g+8i

    // preload vq B-fragments for all 8 k-steps (persistent, reused every entry)
    bf16x8 vqf[8];
#pragma unroll
    for (int s = 0; s < 8; ++s)
        vqf[s] = *(const bf16x8*)(vqb + (b0 + l) * D + 32 * s + 8 * q);

    fx4 zero4 = {0.f, 0.f, 0.f, 0.f};
    fx4 acc[16];
#pragma unroll
    for (int dt = 0; dt < 16; ++dt) acc[dt] = zero4;

    int m0 = blockIdx.x * EPB;
    const float4* emb4 = (const float4*)emb;

    for (int e = 0; e < EPB; ++e) {
        int m = m0 + e;
        __syncthreads();                   // prev entry's PV reads done
        // ---- stage E (bf16, both layouts) ----
        const int* ent = entries + m * N;
        int id = ent[sn];
        const float4* rowp = emb4 + id * (D / 4);
        float msk = (id != 0) ? 1.f : 0.f;
#pragma unroll
        for (int i = 0; i < 8; ++i) {
            int d4 = sg + 8 * i;
            float4 v = rowp[d4];
            u16 h0 = f2bf(v.x * msk), h1 = f2bf(v.y * msk);
            u16 h2 = f2bf(v.z * msk), h3 = f2bf(v.w * msk);
            unsigned int lo = (unsigned int)h0 | ((unsigned int)h1 << 16);
            unsigned int hi = (unsigned int)h2 | ((unsigned int)h3 << 16);
            *(uint2*)&sEu[sn * STR_E + d4 * 4] = make_uint2(lo, hi);
            int db = d4 * 4;
            sETu[(db + 0) * STR_ET + sn] = h0;
            sETu[(db + 1) * STR_ET + sn] = h1;
            sETu[(db + 2) * STR_ET + sn] = h2;
            sETu[(db + 3) * STR_ET + sn] = h3;
        }
        if (t < B) sw[t] = wTp[m * B + t];
        __syncthreads();
        // ---- S^T = E . vq^T ----
        fx4 accS[2];
        accS[0] = zero4; accS[1] = zero4;
#pragma unroll
        for (int T = 0; T < 2; ++T)
#pragma unroll
            for (int s = 0; s < 8; ++s) {
                bf16x8 ea = *(const bf16x8*)&sEu[(16 * T + l) * STR_E + 32 * s + 8 * q];
                accS[T] = __builtin_amdgcn_mfma_f32_16x16x32_bf16(ea, vqf[s], accS[T], 0, 0, 0);
            }
        // ---- softmax over n (lane holds n = 16T + 4q + r at b = b0 + l) ----
        float swb = sw[b0 + l];
        float mx = -INFINITY;
#pragma unroll
        for (int T = 0; T < 2; ++T)
#pragma unroll
            for (int r = 0; r < 4; ++r) mx = fmaxf(mx, accS[T][r]);
        mx = fmaxf(mx, __shfl_xor(mx, 16));
        mx = fmaxf(mx, __shfl_xor(mx, 32));
        float pe[2][4], sum = 0.f;
#pragma unroll
        for (int T = 0; T < 2; ++T)
#pragma unroll
            for (int r = 0; r < 4; ++r) {
                pe[T][r] = __expf(accS[T][r] - mx);
                sum += pe[T][r];
            }
        sum += __shfl_xor(sum, 16);
        sum += __shfl_xor(sum, 32);
        float sc = swb / sum;
        // ---- write P (bf16, b-major) ----
#pragma unroll
        for (int T = 0; T < 2; ++T) {
            u16 p0 = f2bf(pe[T][0] * sc), p1 = f2bf(pe[T][1] * sc);
            u16 p2 = f2bf(pe[T][2] * sc), p3 = f2bf(pe[T][3] * sc);
            unsigned int lo = (unsigned int)p0 | ((unsigned int)p1 << 16);
            unsigned int hi = (unsigned int)p2 | ((unsigned int)p3 << 16);
            *(uint2*)&sPu[(b0 + l) * STR_P + 16 * T + 4 * q] = make_uint2(lo, hi);
        }
        __syncthreads();
        // ---- PV: combined += P . E ----
        bf16x8 pa = *(const bf16x8*)&sPu[(b0 + l) * STR_P + 8 * q];
#pragma unroll
        for (int dt = 0; dt < 16; ++dt) {
            bf16x8 eb = *(const bf16x8*)&sETu[(16 * dt + l) * STR_ET + 8 * q];
            acc[dt] = __builtin_amdgcn_mfma_f32_16x16x32_bf16(pa, eb, acc[dt], 0, 0, 0);
        }
    }
    // ---- epilogue: lane (q,l) reg r holds combined[b0+4q+r][16dt+l] ----
#pragma unroll
    for (int dt = 0; dt < 16; ++dt)
#pragma unroll
        for (int r = 0; r < 4; ++r)
            atomicAdd(&comb[(b0 + 4 * q + r) * D + 16 * dt + l], acc[dt][r]);
}

extern "C" void kernel_launch(void* const* d_in, const int* in_sizes, int n_in,
                              void* d_out, int out_size, void* d_ws, size_t ws_size,
                              hipStream_t stream) {
    const int*   keys    = (const int*)d_in[0];
    const int*   entries = (const int*)d_in[1];
    const float* query   = (const float*)d_in[2];
    const float* wordemb = (const float*)d_in[3];
    const float* qproj_w = (const float*)d_in[4];
    const float* qproj_b = (const float*)d_in[5];

    float* out   = (float*)d_out;
    float* o_k   = out;
    float* lg    = out + B * D;
    float* comb  = out + B * D + B * M;

    float* ws     = (float*)d_ws;
    u16*   vqb    = (u16*)ws;                  // 16384 u16 (fits in old 16384-float slot)
    float* keys_e = ws + 16384;                // 2,048,000 f
    float* wT     = keys_e + M * D;            // 512,000 f
    float* rmax   = wT + M * B;                // 64
    float* rsinv  = rmax + 64;                 // 64

    hipMemsetAsync(o_k, 0, B * D * sizeof(float), stream);
    hipMemsetAsync(comb, 0, B * D * sizeof(float), stream);

    k_vq<<<B, 256, 0, stream>>>(query, qproj_w, qproj_b, vqb);
    k_embed_keys<<<(M * (D / 4)) / 256, 256, 0, stream>>>(keys, wordemb, keys_e);
    k_logits<<<M / 32, 256, 0, stream>>>(query, keys_e, lg);
    k_stats<<<B, 256, 0, stream>>>(lg, rmax, rsinv);
    k_w<<<(M * B) / 256, 256, 0, stream>>>(lg, rmax, rsinv, wT);
    k_ok<<<128, 256, 0, stream>>>(keys_e, wT, o_k);
    k_heavy<<<M / EPB, 256, 0, stream>>>(entries, wordemb, vqb, wT, comb);
}

// Round 3
// 225.953 us; speedup vs baseline: 3.3830x; 1.1739x over previous
//
#include <hip/hip_runtime.h>
#include <math.h>

#define B 64
#define D 256
#define M 8000
#define N 32
#define LG_LD 8000
#define EPB 16

typedef unsigned short u16;
typedef __bf16 bf16x8 __attribute__((ext_vector_type(8)));
typedef float fx4 __attribute__((ext_vector_type(4)));

#define STR_E  264   // u16 stride of sE rows (n-major), 528B = 33*16 aligned
#define STR_ET 40    // u16 stride of sET rows (d-major), 80B = 5*16 aligned
#define STR_P  40    // u16 stride of sP rows (b-major)

static __device__ __forceinline__ u16 f2bf(float x) {
    unsigned int u = __float_as_uint(x);
    u += 0x7FFFu + ((u >> 16) & 1u);
    return (u16)(u >> 16);
}

// ---------------- fused: embed keys (blocks 0..1999) + vq projection (2000..2063) ----------------
__global__ __launch_bounds__(256) void k_pre(const int* __restrict__ keys,
                                             const float* __restrict__ emb,
                                             const float* __restrict__ q,
                                             const float* __restrict__ W,
                                             const float* __restrict__ bias,
                                             float* __restrict__ keys_e,
                                             u16* __restrict__ vqb) {
    __shared__ float qs[D];
    int t = threadIdx.x;
    if (blockIdx.x < 2000) {
        int gid = blockIdx.x * 256 + t;          // over 8000*64 float4s
        int j = gid >> 6, qq = gid & 63;
        int id = keys[j];
        const float4* emb4 = (const float4*)emb;
        float4 v = emb4[id * (D / 4) + qq];
        if (id == 0) { v.x = 0.f; v.y = 0.f; v.z = 0.f; v.w = 0.f; }
        ((float4*)keys_e)[j * (D / 4) + qq] = v;
    } else {
        int b = blockIdx.x - 2000;
        qs[t] = q[b * D + t];
        __syncthreads();
        const float* wr = W + t * D;
        float acc = bias[t];
#pragma unroll 8
        for (int k = 0; k < D; k += 4) {
            float4 w4 = *(const float4*)(wr + k);
            acc += qs[k] * w4.x + qs[k + 1] * w4.y + qs[k + 2] * w4.z + qs[k + 3] * w4.w;
        }
        vqb[b * D + t] = f2bf(acc);
    }
}

// ---------------- logits_e = query @ keys_e^T  (64 x 8000, fp32, q staged in LDS) ----------------
__global__ __launch_bounds__(256) void k_logits(const float* __restrict__ q,
                                                const float* __restrict__ keys_e,
                                                float* __restrict__ out_lg) {
    __shared__ float ks[32 * 260];   // 33,280 B
    __shared__ float qs[64 * 260];   // 66,560 B  (1 block/CU; 250 blocks)
    int t = threadIdx.x;
    int j0 = blockIdx.x * 32;
    for (int i = 0; i < 32; ++i)
        ks[i * 260 + t] = keys_e[(j0 + i) * D + t];
    for (int i = 0; i < 64; ++i)
        qs[i * 260 + t] = q[i * D + t];
    __syncthreads();
    int tx = t & 15, ty = t >> 4;
    float acc[4][2] = {};
    for (int k = 0; k < D; k += 4) {
        float4 c0 = *(const float4*)&ks[tx * 260 + k];
        float4 c1 = *(const float4*)&ks[(tx + 16) * 260 + k];
#pragma unroll
        for (int i = 0; i < 4; ++i) {
            float4 a = *(const float4*)&qs[(ty + 16 * i) * 260 + k];
            acc[i][0] += a.x * c0.x + a.y * c0.y + a.z * c0.z + a.w * c0.w;
            acc[i][1] += a.x * c1.x + a.y * c1.y + a.z * c1.z + a.w * c1.w;
        }
    }
#pragma unroll
    for (int i = 0; i < 4; ++i) {
        out_lg[(ty + 16 * i) * LG_LD + j0 + tx] = acc[i][0];
        out_lg[(ty + 16 * i) * LG_LD + j0 + tx + 16] = acc[i][1];
    }
}

// ---------------- per-b row max & 1/sum(exp) over m ----------------
__global__ __launch_bounds__(256) void k_stats(const float* __restrict__ lg,
                                               float* __restrict__ rmax,
                                               float* __restrict__ rsinv) {
    int b = blockIdx.x, t = threadIdx.x;
    __shared__ float red[256];
    const float* row = lg + b * LG_LD;
    float mx = -INFINITY;
    for (int j = t; j < M; j += 256) mx = fmaxf(mx, row[j]);
    red[t] = mx; __syncthreads();
    for (int s = 128; s > 0; s >>= 1) {
        if (t < s) red[t] = fmaxf(red[t], red[t + s]);
        __syncthreads();
    }
    mx = red[0]; __syncthreads();
    float sm = 0.f;
    for (int j = t; j < M; j += 256) sm += __expf(row[j] - mx);
    red[t] = sm; __syncthreads();
    for (int s = 128; s > 0; s >>= 1) {
        if (t < s) red[t] += red[t + s];
        __syncthreads();
    }
    if (t == 0) { rmax[b] = mx; rsinv[b] = 1.f / red[0]; }
}

// ---------------- wT[m][b] = prob_e[b][m]  (LDS transpose, coalesced both sides) ----------------
__global__ __launch_bounds__(256) void k_w(const float* __restrict__ lg,
                                           const float* __restrict__ rmax,
                                           const float* __restrict__ rsinv,
                                           float* __restrict__ wT) {
    __shared__ float tile[64][65];
    int t = threadIdx.x;
    int x = t & 63, y = t >> 6;
    int m0 = blockIdx.x * 64;           // 125 blocks
#pragma unroll
    for (int i = 0; i < 16; ++i) {
        int b = 4 * i + y;
        tile[b][x] = __expf(lg[b * LG_LD + m0 + x] - rmax[b]) * rsinv[b];
    }
    __syncthreads();
#pragma unroll
    for (int i = 0; i < 16; ++i) {
        int m = 4 * i + y;
        wT[(m0 + m) * 64 + x] = tile[x][m];
    }
}

// ---------------- o_k = prob_e @ keys_e ----------------
__global__ __launch_bounds__(256) void k_ok(const float* __restrict__ keys_e,
                                            const float* __restrict__ wT,
                                            float* __restrict__ o_k) {
    int t = threadIdx.x;
    int bg = blockIdx.x >> 5;
    int jc = blockIdx.x & 31;
    int j0 = jc * 250;
    float acc[16] = {};
    for (int j = j0; j < j0 + 250; ++j) {
        float kv = keys_e[j * D + t];
        const float4* w4 = (const float4*)(wT + j * 64 + bg * 16);
        float4 wa = w4[0], wb = w4[1], wc = w4[2], wd = w4[3];
        acc[0]  += wa.x * kv; acc[1]  += wa.y * kv; acc[2]  += wa.z * kv; acc[3]  += wa.w * kv;
        acc[4]  += wb.x * kv; acc[5]  += wb.y * kv; acc[6]  += wb.z * kv; acc[7]  += wb.w * kv;
        acc[8]  += wc.x * kv; acc[9]  += wc.y * kv; acc[10] += wc.z * kv; acc[11] += wc.w * kv;
        acc[12] += wd.x * kv; acc[13] += wd.y * kv; acc[14] += wd.z * kv; acc[15] += wd.w * kv;
    }
#pragma unroll
    for (int i = 0; i < 16; ++i)
        atomicAdd(&o_k[(bg * 16 + i) * D + t], acc[i]);
}

// ---------------- heavy: per-entry value attention via bf16 MFMA ----------------
// Coalesced full-row gather (4 rows x 256B contiguous per wave instr) + 2-deep
// register prefetch pipeline (ids 2 entries ahead, row data 1 entry ahead).
// sET writes bank-swizzled: column = row ^ 8*((d>>2)&3).
__global__ __launch_bounds__(256, 2) void k_heavy(const int* __restrict__ entries,
                                                  const float* __restrict__ emb,
                                                  const u16* __restrict__ vqb,
                                                  const float* __restrict__ wTp,
                                                  float* __restrict__ comb) {
    __shared__ __align__(16) u16 sEu[N * STR_E];     // 16,896 B  row-major E (n x d)
    __shared__ __align__(16) u16 sETu[D * STR_ET];   // 20,480 B  transposed E (d x n), swizzled
    __shared__ __align__(16) u16 sPu[B * STR_P];     //  5,120 B  P (b x n)
    __shared__ float sw[B];

    int t = threadIdx.x;
    int lane = t & 63, l = lane & 15, q = lane >> 4, w = t >> 6;
    int b0 = 16 * w;
    int ri = lane >> 4, sl = lane & 15;    // gather: quarter-wave row, slot-in-row

    // preload vq B-fragments (persistent across all entries)
    bf16x8 vqf[8];
#pragma unroll
    for (int s = 0; s < 8; ++s)
        vqf[s] = *(const bf16x8*)(vqb + (b0 + l) * D + 32 * s + 8 * q);

    fx4 zero4 = {0.f, 0.f, 0.f, 0.f};
    fx4 acc[16];
#pragma unroll
    for (int dt = 0; dt < 16; ++dt) acc[dt] = zero4;

    int m0 = blockIdx.x * EPB;
    const float4* emb4 = (const float4*)emb;

    // pipeline prologue: ids for e=0, rows for e=0, ids for e=1
    int idcA = entries[m0 * N + 8 * w + ri];
    int idcB = entries[m0 * N + 8 * w + ri + 4];
    float4 pf[8];
#pragma unroll
    for (int i = 0; i < 8; ++i) {
        int id = (i & 1) ? idcB : idcA;
        pf[i] = emb4[id * (D / 4) + sl + 16 * (i >> 1)];
    }
    int idnA = entries[(m0 + 1) * N + 8 * w + ri];
    int idnB = entries[(m0 + 1) * N + 8 * w + ri + 4];

    for (int e = 0; e < EPB; ++e) {
        __syncthreads();                   // prev entry's PV reads of LDS done
        // ---- staging: write entry e's rows (held in pf) to sE / sET ----
#pragma unroll
        for (int i = 0; i < 8; ++i) {
            int id = (i & 1) ? idcB : idcA;
            float msk = (id != 0) ? 1.f : 0.f;
            int row = 8 * w + ri + 4 * (i & 1);
            int slot = sl + 16 * (i >> 1);
            float4 v = pf[i];
            u16 h0 = f2bf(v.x * msk), h1 = f2bf(v.y * msk);
            u16 h2 = f2bf(v.z * msk), h3 = f2bf(v.w * msk);
            unsigned int lo = (unsigned int)h0 | ((unsigned int)h1 << 16);
            unsigned int hi = (unsigned int)h2 | ((unsigned int)h3 << 16);
            *(uint2*)&sEu[row * STR_E + slot * 4] = make_uint2(lo, hi);
            int d0 = slot * 4;
            int rowp = row ^ (8 * (slot & 3));   // bank swizzle
            sETu[(d0 + 0) * STR_ET + rowp] = h0;
            sETu[(d0 + 1) * STR_ET + rowp] = h1;
            sETu[(d0 + 2) * STR_ET + rowp] = h2;
            sETu[(d0 + 3) * STR_ET + rowp] = h3;
        }
        if (t < B) sw[t] = wTp[(m0 + e) * B + t];
        // ---- prefetch entry e+1 rows (pf regs now free), then e+2 ids ----
        if (e + 1 < EPB) {
            int a = idnA, b2 = idnB;
#pragma unroll
            for (int i = 0; i < 8; ++i) {
                int id = (i & 1) ? b2 : a;
                pf[i] = emb4[id * (D / 4) + sl + 16 * (i >> 1)];
            }
            idcA = a; idcB = b2;
            if (e + 2 < EPB) {
                idnA = entries[(m0 + e + 2) * N + 8 * w + ri];
                idnB = entries[(m0 + e + 2) * N + 8 * w + ri + 4];
            }
        }
        __syncthreads();
        // ---- S^T = E . vq^T ----
        fx4 accS[2];
        accS[0] = zero4; accS[1] = zero4;
#pragma unroll
        for (int T = 0; T < 2; ++T)
#pragma unroll
            for (int s = 0; s < 8; ++s) {
                bf16x8 ea = *(const bf16x8*)&sEu[(16 * T + l) * STR_E + 32 * s + 8 * q];
                accS[T] = __builtin_amdgcn_mfma_f32_16x16x32_bf16(ea, vqf[s], accS[T], 0, 0, 0);
            }
        // ---- softmax over n (lane: n = 16T + 4q + r at b = b0 + l), fold prob_e ----
        float swb = sw[b0 + l];
        float mx = -INFINITY;
#pragma unroll
        for (int T = 0; T < 2; ++T)
#pragma unroll
            for (int r = 0; r < 4; ++r) mx = fmaxf(mx, accS[T][r]);
        mx = fmaxf(mx, __shfl_xor(mx, 16));
        mx = fmaxf(mx, __shfl_xor(mx, 32));
        float pe[2][4], sum = 0.f;
#pragma unroll
        for (int T = 0; T < 2; ++T)
#pragma unroll
            for (int r = 0; r < 4; ++r) {
                pe[T][r] = __expf(accS[T][r] - mx);
                sum += pe[T][r];
            }
        sum += __shfl_xor(sum, 16);
        sum += __shfl_xor(sum, 32);
        float sc = swb / sum;
        // ---- write P (bf16, b-major) ----
#pragma unroll
        for (int T = 0; T < 2; ++T) {
            u16 p0 = f2bf(pe[T][0] * sc), p1 = f2bf(pe[T][1] * sc);
            u16 p2 = f2bf(pe[T][2] * sc), p3 = f2bf(pe[T][3] * sc);
            unsigned int lo = (unsigned int)p0 | ((unsigned int)p1 << 16);
            unsigned int hi = (unsigned int)p2 | ((unsigned int)p3 << 16);
            *(uint2*)&sPu[(b0 + l) * STR_P + 16 * T + 4 * q] = make_uint2(lo, hi);
        }
        __syncthreads();
        // ---- PV: combined += P . E ----
        bf16x8 pa = *(const bf16x8*)&sPu[(b0 + l) * STR_P + 8 * q];
#pragma unroll
        for (int dt = 0; dt < 16; ++dt) {
            bf16x8 eb = *(const bf16x8*)&sETu[(16 * dt + l) * STR_ET + 8 * (q ^ ((l >> 2) & 3))];
            acc[dt] = __builtin_amdgcn_mfma_f32_16x16x32_bf16(pa, eb, acc[dt], 0, 0, 0);
        }
    }
    // ---- epilogue: lane (q,l) reg r holds combined[b0+4q+r][16dt+l] ----
#pragma unroll
    for (int dt = 0; dt < 16; ++dt)
#pragma unroll
        for (int r = 0; r < 4; ++r)
            atomicAdd(&comb[(b0 + 4 * q + r) * D + 16 * dt + l], acc[dt][r]);
}

extern "C" void kernel_launch(void* const* d_in, const int* in_sizes, int n_in,
                              void* d_out, int out_size, void* d_ws, size_t ws_size,
                              hipStream_t stream) {
    const int*   keys    = (const int*)d_in[0];
    const int*   entries = (const int*)d_in[1];
    const float* query   = (const float*)d_in[2];
    const float* wordemb = (const float*)d_in[3];
    const float* qproj_w = (const float*)d_in[4];
    const float* qproj_b = (const float*)d_in[5];

    float* out   = (float*)d_out;
    float* o_k   = out;
    float* lg    = out + B * D;
    float* comb  = out + B * D + B * M;

    float* ws     = (float*)d_ws;
    u16*   vqb    = (u16*)ws;                  // 16384 u16
    float* keys_e = ws + 16384;                // 2,048,000 f
    float* wT     = keys_e + M * D;            // 512,000 f
    float* rmax   = wT + M * B;                // 64
    float* rsinv  = rmax + 64;                 // 64

    hipMemsetAsync(o_k, 0, B * D * sizeof(float), stream);
    hipMemsetAsync(comb, 0, B * D * sizeof(float), stream);

    k_pre<<<2064, 256, 0, stream>>>(keys, wordemb, query, qproj_w, qproj_b, keys_e, vqb);
    k_logits<<<M / 32, 256, 0, stream>>>(query, keys_e, lg);
    k_stats<<<B, 256, 0, stream>>>(lg, rmax, rsinv);
    k_w<<<M / 64, 256, 0, stream>>>(lg, rmax, rsinv, wT);
    k_ok<<<128, 256, 0, stream>>>(keys_e, wT, o_k);
    k_heavy<<<M / EPB, 256, 0, stream>>>(entries, wordemb, vqb, wT, comb);
}